// Round 1
// baseline (11550.346 us; speedup 1.0000x reference)
//
#include <hip/hip_runtime.h>

#define BB 2
#define TT 2048
#define DD 1024
#define HH 16
#define LL 12
#define VV 50257
#define HDD 64
#define FF 4096
#define MM (BB*TT)   // 4096 rows

typedef __bf16 bf16;
typedef __bf16 bf16x8 __attribute__((ext_vector_type(8)));
typedef float  f32x4  __attribute__((ext_vector_type(4)));

// ---------------------------------------------------------------- embedding
__global__ __launch_bounds__(256) void k_embed(const int* __restrict__ x,
    const float* __restrict__ tok, const float* __restrict__ pos,
    float* __restrict__ h)
{
    int row = blockIdx.x;            // 0..4095 = b*T + t
    int t   = row & (TT - 1);
    int idx = x[row];
    int c   = threadIdx.x * 4;
    float4 a = *(const float4*)(tok + (size_t)idx * DD + c);
    float4 p = *(const float4*)(pos + (size_t)t   * DD + c);
    a.x += p.x; a.y += p.y; a.z += p.z; a.w += p.w;
    *(float4*)(h + (size_t)row * DD + c) = a;
}

// ---------------------------------------------------------------- layernorm
__global__ __launch_bounds__(256) void k_ln(const float* __restrict__ in,
    const float* __restrict__ g, const float* __restrict__ b,
    float* __restrict__ outf, bf16* __restrict__ outb)
{
    int row = blockIdx.x, tid = threadIdx.x;
    const float4 v = *(const float4*)(in + (size_t)row * DD + tid * 4);
    float s  = v.x + v.y + v.z + v.w;
    float s2 = v.x*v.x + v.y*v.y + v.z*v.z + v.w*v.w;
    #pragma unroll
    for (int d = 1; d < 64; d <<= 1) { s += __shfl_xor(s, d); s2 += __shfl_xor(s2, d); }
    __shared__ float red[8];
    __shared__ float mv[2];
    int wid = tid >> 6, lane = tid & 63;
    if (lane == 0) { red[2*wid] = s; red[2*wid+1] = s2; }
    __syncthreads();
    if (tid == 0) {
        float ts  = red[0] + red[2] + red[4] + red[6];
        float ts2 = red[1] + red[3] + red[5] + red[7];
        float mean = ts * (1.0f / DD);
        float var  = ts2 * (1.0f / DD) - mean * mean;
        mv[0] = mean; mv[1] = 1.0f / sqrtf(var + 1e-5f);
    }
    __syncthreads();
    float mean = mv[0], inv = mv[1];
    float4 gg = *(const float4*)(g + tid * 4);
    float4 bb = *(const float4*)(b + tid * 4);
    float o0 = (v.x - mean) * inv * gg.x + bb.x;
    float o1 = (v.y - mean) * inv * gg.y + bb.y;
    float o2 = (v.z - mean) * inv * gg.z + bb.z;
    float o3 = (v.w - mean) * inv * gg.w + bb.w;
    size_t o = (size_t)row * DD + tid * 4;
    if (outf) { float4 r = {o0, o1, o2, o3}; *(float4*)(outf + o) = r; }
    if (outb) { outb[o] = (bf16)o0; outb[o+1] = (bf16)o1; outb[o+2] = (bf16)o2; outb[o+3] = (bf16)o3; }
}

// ---------------------------------------------------------------- GEMM
// C[M,N] = A_bf16[M,K] @ B_f32[K,N] (+bias) (+res) (relu?) -> f32 and/or bf16*scale
// 128x128 tile, BK=32, 4 waves (2x2), mfma 16x16x32 bf16.
__global__ __launch_bounds__(256) void k_gemm(
    const bf16* __restrict__ A, const float* __restrict__ Bm,
    const float* __restrict__ bias, const float* __restrict__ res,
    float* __restrict__ outf, bf16* __restrict__ outb,
    int M, int N, int K, int relu, float bscale)
{
    __shared__ alignas(16) bf16 lA[128][40];   // [m][k], pad keeps 16B rows
    __shared__ alignas(16) bf16 lB[128][40];   // [n][k] (transposed)
    int tid  = threadIdx.x;
    int lane = tid & 63, wid = tid >> 6;
    int wm = wid >> 1, wn = wid & 1;
    int n0 = blockIdx.x * 128, m0 = blockIdx.y * 128;
    int r16 = lane & 15, g4 = lane >> 4;

    f32x4 acc[4][4];
    const f32x4 fzero = {0.f, 0.f, 0.f, 0.f};
    #pragma unroll
    for (int i = 0; i < 4; i++)
        #pragma unroll
        for (int j = 0; j < 4; j++) acc[i][j] = fzero;

    int arow = tid >> 2, aseg = tid & 3;      // A staging: 2 rows x 16B
    int bkr  = tid >> 3, bnb  = tid & 7;      // B staging: row k, 16 floats
    bool nfull = (n0 + 128 <= N);
    bool fast  = nfull && ((N & 3) == 0);     // float4-aligned B rows

    for (int k0 = 0; k0 < K; k0 += 32) {
        *(uint4*)&lA[arow][aseg*8] =
            *(const uint4*)(A + (size_t)(m0 + arow) * K + k0 + aseg*8);
        *(uint4*)&lA[arow + 64][aseg*8] =
            *(const uint4*)(A + (size_t)(m0 + arow + 64) * K + k0 + aseg*8);

        const float* bsrc = Bm + (size_t)(k0 + bkr) * N + n0;
        if (fast) {
            #pragma unroll
            for (int q = 0; q < 4; q++) {
                int n = q*32 + bnb*4;
                float4 f = *(const float4*)(bsrc + n);
                lB[n  ][bkr] = (bf16)f.x;
                lB[n+1][bkr] = (bf16)f.y;
                lB[n+2][bkr] = (bf16)f.z;
                lB[n+3][bkr] = (bf16)f.w;
            }
        } else {
            #pragma unroll
            for (int q = 0; q < 4; q++) {
                int n = q*32 + bnb*4;
                #pragma unroll
                for (int i = 0; i < 4; i++) {
                    float fv = 0.0f;
                    if (nfull || (n0 + n + i < N)) fv = bsrc[n + i];
                    lB[n+i][bkr] = (bf16)fv;
                }
            }
        }
        __syncthreads();

        int kb = g4 * 8;
        bf16x8 af[4], bfr[4];
        #pragma unroll
        for (int mi = 0; mi < 4; mi++)
            af[mi] = *(const bf16x8*)&lA[wm*64 + mi*16 + r16][kb];
        #pragma unroll
        for (int ni = 0; ni < 4; ni++)
            bfr[ni] = *(const bf16x8*)&lB[wn*64 + ni*16 + r16][kb];
        #pragma unroll
        for (int mi = 0; mi < 4; mi++)
            #pragma unroll
            for (int ni = 0; ni < 4; ni++)
                acc[mi][ni] = __builtin_amdgcn_mfma_f32_16x16x32_bf16(
                    af[mi], bfr[ni], acc[mi][ni], 0, 0, 0);
        __syncthreads();
    }

    #pragma unroll
    for (int ni = 0; ni < 4; ni++) {
        int col = n0 + wn*64 + ni*16 + r16;
        if (col >= N) continue;
        float bi = bias ? bias[col] : 0.0f;
        #pragma unroll
        for (int mi = 0; mi < 4; mi++) {
            #pragma unroll
            for (int j = 0; j < 4; j++) {
                int row = m0 + wm*64 + mi*16 + g4*4 + j;
                float vv = acc[mi][ni][j] + bi;
                if (res)  vv += res[(size_t)row * N + col];
                if (relu) vv = fmaxf(vv, 0.0f);
                if (outf) outf[(size_t)row * N + col] = vv;
                if (outb) outb[(size_t)row * N + col] = (bf16)(vv * bscale);
            }
        }
    }
}

// ---------------------------------------------------------------- attention
// q,k,v,o: [B,T,D] bf16, head h = cols h*64..h*64+63. q pre-scaled by 1/8.
// grid (T/64, B*H), 4 waves, wave owns 16 q rows; KV tiles of 32, online softmax.
__global__ __launch_bounds__(256) void k_attn(
    const bf16* __restrict__ q, const bf16* __restrict__ k,
    const bf16* __restrict__ v, bf16* __restrict__ o)
{
    __shared__ alignas(16) bf16 lK[32][72];      // [s][hd]
    __shared__ alignas(16) bf16 lVT[64][40];     // [hd][s]
    __shared__ alignas(16) bf16 lP[4][16][40];   // per-wave P tile [qrow][s]
    int tid = threadIdx.x, lane = tid & 63, wid = tid >> 6;
    int t0 = blockIdx.x * 64;
    int bh = blockIdx.y;
    int bb = bh >> 4, hh = bh & 15;              // H = 16
    const size_t base = ((size_t)bb * TT) * DD + (size_t)hh * HDD;
    const bf16* qp = q + base;
    const bf16* kp = k + base;
    const bf16* vp = v + base;
    bf16*       op = o + base;
    int r16 = lane & 15, g4 = lane >> 4;

    bf16x8 qf[2];
    {
        const bf16* qr = qp + (size_t)(t0 + wid*16 + r16) * DD + g4*8;
        qf[0] = *(const bf16x8*)qr;
        qf[1] = *(const bf16x8*)(qr + 32);
    }
    f32x4 oacc[4];
    const f32x4 fzero = {0.f, 0.f, 0.f, 0.f};
    #pragma unroll
    for (int i = 0; i < 4; i++) oacc[i] = fzero;
    float mrow[4] = {-1e30f, -1e30f, -1e30f, -1e30f};
    float lrow[4] = {0.f, 0.f, 0.f, 0.f};

    int sr = tid >> 3, sseg = tid & 7;           // KV staging coords
    int tlimit = t0 + 64;
    for (int s0 = 0; s0 < tlimit; s0 += 32) {
        *(uint4*)&lK[sr][sseg*8] =
            *(const uint4*)(kp + (size_t)(s0 + sr) * DD + sseg*8);
        {
            bf16x8 vv = *(const bf16x8*)(vp + (size_t)(s0 + sr) * DD + sseg*8);
            #pragma unroll
            for (int i = 0; i < 8; i++) lVT[sseg*8 + i][sr] = vv[i];
        }
        __syncthreads();

        f32x4 sf[2];
        sf[0] = fzero; sf[1] = fzero;
        #pragma unroll
        for (int nf = 0; nf < 2; nf++)
            #pragma unroll
            for (int ks = 0; ks < 2; ks++) {
                bf16x8 kfr = *(const bf16x8*)&lK[nf*16 + r16][ks*32 + g4*8];
                sf[nf] = __builtin_amdgcn_mfma_f32_16x16x32_bf16(
                    qf[ks], kfr, sf[nf], 0, 0, 0);
            }
        int trow = t0 + wid*16 + g4*4;
        #pragma unroll
        for (int nf = 0; nf < 2; nf++)
            #pragma unroll
            for (int j = 0; j < 4; j++) {
                int ss = s0 + nf*16 + r16;
                if (ss > trow + j) sf[nf][j] = -1e30f;
            }
        float pm[4], al[4], ps[4];
        #pragma unroll
        for (int j = 0; j < 4; j++) pm[j] = fmaxf(sf[0][j], sf[1][j]);
        #pragma unroll
        for (int d = 1; d < 16; d <<= 1)
            #pragma unroll
            for (int j = 0; j < 4; j++) pm[j] = fmaxf(pm[j], __shfl_xor(pm[j], d));
        #pragma unroll
        for (int j = 0; j < 4; j++) {
            float mn = fmaxf(mrow[j], pm[j]);
            al[j] = __expf(mrow[j] - mn);
            mrow[j] = mn;
            ps[j] = 0.f;
        }
        #pragma unroll
        for (int nf = 0; nf < 2; nf++)
            #pragma unroll
            for (int j = 0; j < 4; j++) {
                float p = __expf(sf[nf][j] - mrow[j]);
                ps[j] += p;
                lP[wid][g4*4 + j][nf*16 + r16] = (bf16)p;
            }
        #pragma unroll
        for (int d = 1; d < 16; d <<= 1)
            #pragma unroll
            for (int j = 0; j < 4; j++) ps[j] += __shfl_xor(ps[j], d);
        #pragma unroll
        for (int j = 0; j < 4; j++) lrow[j] = lrow[j] * al[j] + ps[j];
        #pragma unroll
        for (int nf = 0; nf < 4; nf++)
            #pragma unroll
            for (int j = 0; j < 4; j++) oacc[nf][j] *= al[j];
        __syncthreads();

        bf16x8 pa = *(const bf16x8*)&lP[wid][r16][g4*8];
        #pragma unroll
        for (int nf = 0; nf < 4; nf++) {
            bf16x8 vfr = *(const bf16x8*)&lVT[nf*16 + r16][g4*8];
            oacc[nf] = __builtin_amdgcn_mfma_f32_16x16x32_bf16(
                pa, vfr, oacc[nf], 0, 0, 0);
        }
        __syncthreads();
    }

    #pragma unroll
    for (int nf = 0; nf < 4; nf++) {
        #pragma unroll
        for (int j = 0; j < 4; j++) {
            int trow = t0 + wid*16 + g4*4 + j;
            float val = oacc[nf][j] / lrow[j];
            op[(size_t)trow * DD + nf*16 + r16] = (bf16)val;
        }
    }
}

// ---------------------------------------------------------------- launcher
extern "C" void kernel_launch(void* const* d_in, const int* in_sizes, int n_in,
                              void* d_out, int out_size, void* d_ws, size_t ws_size,
                              hipStream_t stream)
{
    (void)in_sizes; (void)n_in; (void)out_size; (void)ws_size;
    const int*   x    = (const int*)  d_in[0];
    const float* tok  = (const float*)d_in[1];
    const float* pos  = (const float*)d_in[2];
    const float* ln1g = (const float*)d_in[3];
    const float* ln1b = (const float*)d_in[4];
    const float* wq   = (const float*)d_in[5];
    const float* bq   = (const float*)d_in[6];
    const float* wk   = (const float*)d_in[7];
    const float* bk   = (const float*)d_in[8];
    const float* wv   = (const float*)d_in[9];
    const float* bv   = (const float*)d_in[10];
    const float* wo   = (const float*)d_in[11];
    const float* bo   = (const float*)d_in[12];
    const float* ln2g = (const float*)d_in[13];
    const float* ln2b = (const float*)d_in[14];
    const float* w1   = (const float*)d_in[15];
    const float* b1   = (const float*)d_in[16];
    const float* w2   = (const float*)d_in[17];
    const float* b2   = (const float*)d_in[18];
    const float* lnfg = (const float*)d_in[19];
    const float* lnfb = (const float*)d_in[20];
    const float* fcw  = (const float*)d_in[21];
    const float* fcb  = (const float*)d_in[22];

    // Scratch lives inside d_out (823 MB; logits are written last, in the
    // final GEMM, which reads only d_ws + d_in). Final-LN bf16 activation
    // must survive the logits write, so it lives in d_ws (8 MB).
    char*  sb   = (char*)d_out;
    float* h    = (float*)(sb);                  // 16 MB
    float* hn   = (float*)(sb + (16u << 20));    // 16 MB
    bf16*  hnb  = (bf16*) (sb + (32u << 20));    //  8 MB
    bf16*  qb   = (bf16*) (sb + (40u << 20));    //  8 MB
    bf16*  kbuf = (bf16*) (sb + (48u << 20));    //  8 MB
    bf16*  vbuf = (bf16*) (sb + (56u << 20));    //  8 MB
    bf16*  obuf = (bf16*) (sb + (64u << 20));    //  8 MB
    bf16*  f1b  = (bf16*) (sb + (72u << 20));    // 32 MB (ends 104 MB)
    bf16*  hfb  = (bf16*) d_ws;                  //  8 MB

    dim3 blk(256);
    dim3 gD(8, 32);          // N=1024 GEMMs
    dim3 gF(32, 32);         // N=4096 GEMM
    dim3 gV((VV + 127) / 128, 32);

    k_embed<<<MM, blk, 0, stream>>>(x, tok, pos, h);
    for (int l = 0; l < LL; l++) {
        k_ln<<<MM, blk, 0, stream>>>(h, ln1g + l*DD, ln1b + l*DD, hn, hnb);
        k_gemm<<<gD, blk, 0, stream>>>(hnb, wq + (size_t)l*DD*DD, bq + l*DD,
                                       nullptr, nullptr, qb, MM, DD, DD, 0, 0.125f);
        k_gemm<<<gD, blk, 0, stream>>>(hnb, wk + (size_t)l*DD*DD, bk + l*DD,
                                       nullptr, nullptr, kbuf, MM, DD, DD, 0, 1.0f);
        k_gemm<<<gD, blk, 0, stream>>>(hnb, wv + (size_t)l*DD*DD, bv + l*DD,
                                       nullptr, nullptr, vbuf, MM, DD, DD, 0, 1.0f);
        k_attn<<<dim3(TT/64, BB*HH), blk, 0, stream>>>(qb, kbuf, vbuf, obuf);
        k_gemm<<<gD, blk, 0, stream>>>(obuf, wo + (size_t)l*DD*DD, bo + l*DD,
                                       hn, h, nullptr, MM, DD, DD, 0, 1.0f);
        k_ln<<<MM, blk, 0, stream>>>(h, ln2g + l*DD, ln2b + l*DD, hn, hnb);
        k_gemm<<<gF, blk, 0, stream>>>(hnb, w1 + (size_t)l*DD*FF, b1 + l*FF,
                                       nullptr, nullptr, f1b, MM, FF, DD, 1, 1.0f);
        k_gemm<<<gD, blk, 0, stream>>>(f1b, w2 + (size_t)l*FF*DD, b2 + l*DD,
                                       hn, h, nullptr, MM, DD, FF, 0, 1.0f);
    }
    k_ln<<<MM, blk, 0, stream>>>(h, lnfg, lnfb, nullptr, hfb);
    k_gemm<<<gV, blk, 0, stream>>>(hfb, fcw, fcb, nullptr, (float*)d_out,
                                   nullptr, MM, VV, DD, 0, 1.0f);
}

// Round 2
// 7523.212 us; speedup vs baseline: 1.5353x; 1.5353x over previous
//
#include <hip/hip_runtime.h>

#define BB 2
#define TT 2048
#define DD 1024
#define HH 16
#define LL 12
#define VV 50257
#define VP 50304            // V padded to multiple of 128
#define HDD 64
#define FF 4096
#define MM (BB*TT)          // 4096 rows
#define QS 3072             // fused qkv row stride

typedef __bf16 bf16;
typedef __bf16 bf16x8 __attribute__((ext_vector_type(8)));
typedef float  f32x4  __attribute__((ext_vector_type(4)));

typedef const __attribute__((address_space(1))) void* gas_t;
typedef __attribute__((address_space(3))) void* las_t;

// ---------------------------------------------------------------- embedding
__global__ __launch_bounds__(256) void k_embed(const int* __restrict__ x,
    const float* __restrict__ tok, const float* __restrict__ pos,
    float* __restrict__ h)
{
    int row = blockIdx.x;
    int t   = row & (TT - 1);
    int idx = x[row];
    int c   = threadIdx.x * 4;
    float4 a = *(const float4*)(tok + (size_t)idx * DD + c);
    float4 p = *(const float4*)(pos + (size_t)t   * DD + c);
    a.x += p.x; a.y += p.y; a.z += p.z; a.w += p.w;
    *(float4*)(h + (size_t)row * DD + c) = a;
}

// ---------------------------------------------------------------- layernorm
__global__ __launch_bounds__(256) void k_ln(const float* __restrict__ in,
    const float* __restrict__ g, const float* __restrict__ b,
    float* __restrict__ outf, bf16* __restrict__ outb)
{
    int row = blockIdx.x, tid = threadIdx.x;
    const float4 v = *(const float4*)(in + (size_t)row * DD + tid * 4);
    float s  = v.x + v.y + v.z + v.w;
    float s2 = v.x*v.x + v.y*v.y + v.z*v.z + v.w*v.w;
    #pragma unroll
    for (int d = 1; d < 64; d <<= 1) { s += __shfl_xor(s, d); s2 += __shfl_xor(s2, d); }
    __shared__ float red[8];
    __shared__ float mv[2];
    int wid = tid >> 6, lane = tid & 63;
    if (lane == 0) { red[2*wid] = s; red[2*wid+1] = s2; }
    __syncthreads();
    if (tid == 0) {
        float ts  = red[0] + red[2] + red[4] + red[6];
        float ts2 = red[1] + red[3] + red[5] + red[7];
        float mean = ts * (1.0f / DD);
        float var  = ts2 * (1.0f / DD) - mean * mean;
        mv[0] = mean; mv[1] = 1.0f / sqrtf(var + 1e-5f);
    }
    __syncthreads();
    float mean = mv[0], inv = mv[1];
    float4 gg = *(const float4*)(g + tid * 4);
    float4 bb = *(const float4*)(b + tid * 4);
    float o0 = (v.x - mean) * inv * gg.x + bb.x;
    float o1 = (v.y - mean) * inv * gg.y + bb.y;
    float o2 = (v.z - mean) * inv * gg.z + bb.z;
    float o3 = (v.w - mean) * inv * gg.w + bb.w;
    size_t o = (size_t)row * DD + tid * 4;
    if (outf) { float4 r = {o0, o1, o2, o3}; *(float4*)(outf + o) = r; }
    if (outb) { outb[o] = (bf16)o0; outb[o+1] = (bf16)o1; outb[o+2] = (bf16)o2; outb[o+3] = (bf16)o3; }
}

// ---------------------------------------------------------------- weight transpose+convert
// src f32 [K][N] (layer l at src + l*srcLS) -> dst bf16 [n][K] rows n0..; zero-pad n >= N.
__global__ __launch_bounds__(256) void k_wtrans(
    const float* __restrict__ src, bf16* __restrict__ dst,
    int K, int N, int Npad, size_t srcLS, size_t dstLS)
{
    src += (size_t)blockIdx.z * srcLS;
    dst += (size_t)blockIdx.z * dstLS;
    int k0 = blockIdx.y * 32, n0 = blockIdx.x * 256;
    __shared__ float tile[32][256];
    int tid = threadIdx.x;
    bool aligned = ((N & 3) == 0);
    #pragma unroll
    for (int p = 0; p < 8; p++) {
        int kk = p * 4 + (tid >> 6);
        int nn = (tid & 63) * 4;
        float4 v = {0.f, 0.f, 0.f, 0.f};
        const float* sp = src + (size_t)(k0 + kk) * N + n0 + nn;
        if (aligned && (n0 + nn + 3 < N)) {
            v = *(const float4*)sp;
        } else {
            #pragma unroll
            for (int i = 0; i < 4; i++)
                if (n0 + nn + i < N) ((float*)&v)[i] = sp[i];
        }
        *(float4*)&tile[kk][nn] = v;
    }
    __syncthreads();
    int n = n0 + tid;
    if (n < Npad) {
        bf16 rowv[32];
        #pragma unroll
        for (int kk = 0; kk < 32; kk++) rowv[kk] = (bf16)tile[kk][tid];
        bf16* dp = dst + (size_t)n * K + k0;
        #pragma unroll
        for (int s = 0; s < 4; s++)
            *(bf16x8*)(dp + s * 8) = *(const bf16x8*)&rowv[s * 8];
    }
}

// ---------------------------------------------------------------- bias merge (q|k|v)
__global__ __launch_bounds__(256) void k_biasmerge(
    const float* __restrict__ bq, const float* __restrict__ bk,
    const float* __restrict__ bv, float* __restrict__ dst)
{
    int i = blockIdx.x * 256 + threadIdx.x;
    if (i >= LL * QS) return;
    int l = i / QS, j = i % QS;
    float v = (j < 1024) ? bq[l*1024 + j]
            : (j < 2048) ? bk[l*1024 + j - 1024]
                         : bv[l*1024 + j - 2048];
    dst[i] = v;
}

// ---------------------------------------------------------------- GEMM (m97 structure)
// C[M,*] = A_bf16[M,K] @ BT_bf16[n][K]^T (+bias) (+res) (relu?) -> f32 and/or bf16.
// Grid: x = n-blocks (BT rows, padded OK), y = M/128. Out row stride / col guard = Nout.
__global__ __launch_bounds__(256) void k_gemm_bt(
    const bf16* __restrict__ A, const bf16* __restrict__ BT,
    const float* __restrict__ bias, const float* __restrict__ res,
    float* __restrict__ outf, bf16* __restrict__ outb,
    int K, int Nout, int relu)
{
    __shared__ alignas(16) bf16 lA[128 * 64];   // [m][k] linear, 128B rows
    __shared__ alignas(16) bf16 lB[128 * 64];   // [n][k] linear
    int tid = threadIdx.x;
    int lane = tid & 63, w = tid >> 6;
    int wm = w >> 1, wn = w & 1;
    int n0 = blockIdx.x * 128, m0 = blockIdx.y * 128;
    int r16 = lane & 15, g4 = lane >> 4;

    f32x4 acc[4][4];
    const f32x4 fzero = {0.f, 0.f, 0.f, 0.f};
    #pragma unroll
    for (int i = 0; i < 4; i++)
        #pragma unroll
        for (int j = 0; j < 4; j++) acc[i][j] = fzero;

    // per-lane global source row/col for staging chunk i: byte off = i*4096 + w*1024 + lane*16
    int soff = w * 1024 + lane * 16;

    for (int k0 = 0; k0 < K; k0 += 64) {
        #pragma unroll
        for (int i = 0; i < 4; i++) {
            int off = i * 4096 + soff;
            int r = off >> 7, c = (off & 127) >> 1;
            __builtin_amdgcn_global_load_lds(
                (gas_t)(A + (size_t)(m0 + r) * K + k0 + c),
                (las_t)&lA[(i * 4096 + w * 1024) >> 1], 16, 0, 0);
        }
        #pragma unroll
        for (int i = 0; i < 4; i++) {
            int off = i * 4096 + soff;
            int r = off >> 7, c = (off & 127) >> 1;
            __builtin_amdgcn_global_load_lds(
                (gas_t)(BT + (size_t)(n0 + r) * K + k0 + c),
                (las_t)&lB[(i * 4096 + w * 1024) >> 1], 16, 0, 0);
        }
        __syncthreads();

        #pragma unroll
        for (int kh = 0; kh < 2; kh++) {
            bf16x8 af[4], bfr[4];
            #pragma unroll
            for (int mi = 0; mi < 4; mi++)
                af[mi] = *(const bf16x8*)&lA[(wm*64 + mi*16 + r16) * 64 + kh*32 + g4*8];
            #pragma unroll
            for (int ni = 0; ni < 4; ni++)
                bfr[ni] = *(const bf16x8*)&lB[(wn*64 + ni*16 + r16) * 64 + kh*32 + g4*8];
            #pragma unroll
            for (int mi = 0; mi < 4; mi++)
                #pragma unroll
                for (int ni = 0; ni < 4; ni++)
                    acc[mi][ni] = __builtin_amdgcn_mfma_f32_16x16x32_bf16(
                        af[mi], bfr[ni], acc[mi][ni], 0, 0, 0);
        }
        __syncthreads();
    }

    #pragma unroll
    for (int ni = 0; ni < 4; ni++) {
        int col = n0 + wn*64 + ni*16 + r16;
        if (col >= Nout) continue;
        float bi = bias ? bias[col] : 0.0f;
        #pragma unroll
        for (int mi = 0; mi < 4; mi++) {
            #pragma unroll
            for (int j = 0; j < 4; j++) {
                int row = m0 + wm*64 + mi*16 + g4*4 + j;
                float vv = acc[mi][ni][j] + bi;
                if (res)  vv += res[(size_t)row * Nout + col];
                if (relu) vv = fmaxf(vv, 0.0f);
                if (outf) outf[(size_t)row * Nout + col] = vv;
                if (outb) outb[(size_t)row * Nout + col] = (bf16)vv;
            }
        }
    }
}

// ---------------------------------------------------------------- fallback GEMM (f32 B)
// Used only for logits when d_ws can't hold fc_w^T. Grid: x = m-blocks, y = n-blocks.
__global__ __launch_bounds__(256) void k_gemm_f32b(
    const bf16* __restrict__ A, const float* __restrict__ Bm,
    const float* __restrict__ bias, float* __restrict__ outf,
    int M, int N, int K)
{
    __shared__ alignas(16) bf16 lA[128][40];
    __shared__ alignas(16) bf16 lB[128][40];
    int tid  = threadIdx.x;
    int lane = tid & 63, wid = tid >> 6;
    int wm = wid >> 1, wn = wid & 1;
    int m0 = blockIdx.x * 128, n0 = blockIdx.y * 128;
    int r16 = lane & 15, g4 = lane >> 4;

    f32x4 acc[4][4];
    const f32x4 fzero = {0.f, 0.f, 0.f, 0.f};
    #pragma unroll
    for (int i = 0; i < 4; i++)
        #pragma unroll
        for (int j = 0; j < 4; j++) acc[i][j] = fzero;

    int arow = tid >> 2, aseg = tid & 3;
    int bkr  = tid >> 3, bnb  = tid & 7;
    bool nfull = (n0 + 128 <= N);

    for (int k0 = 0; k0 < K; k0 += 32) {
        *(uint4*)&lA[arow][aseg*8] =
            *(const uint4*)(A + (size_t)(m0 + arow) * K + k0 + aseg*8);
        *(uint4*)&lA[arow + 64][aseg*8] =
            *(const uint4*)(A + (size_t)(m0 + arow + 64) * K + k0 + aseg*8);
        const float* bsrc = Bm + (size_t)(k0 + bkr) * N + n0;
        #pragma unroll
        for (int q = 0; q < 4; q++) {
            int n = q*32 + bnb*4;
            #pragma unroll
            for (int i = 0; i < 4; i++) {
                float fv = 0.0f;
                if (nfull || (n0 + n + i < N)) fv = bsrc[n + i];
                lB[n+i][bkr] = (bf16)fv;
            }
        }
        __syncthreads();
        int kb = g4 * 8;
        bf16x8 af[4], bfr[4];
        #pragma unroll
        for (int mi = 0; mi < 4; mi++)
            af[mi] = *(const bf16x8*)&lA[wm*64 + mi*16 + r16][kb];
        #pragma unroll
        for (int ni = 0; ni < 4; ni++)
            bfr[ni] = *(const bf16x8*)&lB[wn*64 + ni*16 + r16][kb];
        #pragma unroll
        for (int mi = 0; mi < 4; mi++)
            #pragma unroll
            for (int ni = 0; ni < 4; ni++)
                acc[mi][ni] = __builtin_amdgcn_mfma_f32_16x16x32_bf16(
                    af[mi], bfr[ni], acc[mi][ni], 0, 0, 0);
        __syncthreads();
    }

    #pragma unroll
    for (int ni = 0; ni < 4; ni++) {
        int col = n0 + wn*64 + ni*16 + r16;
        if (col >= N) continue;
        float bi = bias[col];
        #pragma unroll
        for (int mi = 0; mi < 4; mi++) {
            #pragma unroll
            for (int j = 0; j < 4; j++) {
                int row = m0 + wm*64 + mi*16 + g4*4 + j;
                outf[(size_t)row * N + col] = acc[mi][ni][j] + bi;
            }
        }
    }
}

// ---------------------------------------------------------------- attention
// qkv: [M][3072] bf16 (q|k|v), head h = cols h*64.. within each 1024 chunk.
// o: [M][1024] bf16. Scores scaled by 0.125 in f32.
__global__ __launch_bounds__(256) void k_attn(
    const bf16* __restrict__ qkv, bf16* __restrict__ o)
{
    __shared__ alignas(16) bf16 lK[32][72];
    __shared__ alignas(16) bf16 lVT[64][40];
    __shared__ alignas(16) bf16 lP[4][16][40];
    int tid = threadIdx.x, lane = tid & 63, wid = tid >> 6;
    int t0 = blockIdx.x * 64;
    int bh = blockIdx.y;
    int bb = bh >> 4, hh = bh & 15;
    const size_t brow = (size_t)bb * TT;
    const bf16* qp = qkv + brow * QS + hh * HDD;
    const bf16* kp = qp + 1024;
    const bf16* vp = qp + 2048;
    bf16*       op = o + brow * DD + hh * HDD;
    int r16 = lane & 15, g4 = lane >> 4;

    bf16x8 qf[2];
    {
        const bf16* qr = qp + (size_t)(t0 + wid*16 + r16) * QS + g4*8;
        qf[0] = *(const bf16x8*)qr;
        qf[1] = *(const bf16x8*)(qr + 32);
    }
    f32x4 oacc[4];
    const f32x4 fzero = {0.f, 0.f, 0.f, 0.f};
    #pragma unroll
    for (int i = 0; i < 4; i++) oacc[i] = fzero;
    float mrow[4] = {-1e30f, -1e30f, -1e30f, -1e30f};
    float lrow[4] = {0.f, 0.f, 0.f, 0.f};

    int sr = tid >> 3, sseg = tid & 7;
    int tlimit = t0 + 64;
    for (int s0 = 0; s0 < tlimit; s0 += 32) {
        *(uint4*)&lK[sr][sseg*8] =
            *(const uint4*)(kp + (size_t)(s0 + sr) * QS + sseg*8);
        {
            bf16x8 vv = *(const bf16x8*)(vp + (size_t)(s0 + sr) * QS + sseg*8);
            #pragma unroll
            for (int i = 0; i < 8; i++) lVT[sseg*8 + i][sr] = vv[i];
        }
        __syncthreads();

        f32x4 sf[2];
        sf[0] = fzero; sf[1] = fzero;
        #pragma unroll
        for (int nf = 0; nf < 2; nf++)
            #pragma unroll
            for (int ks = 0; ks < 2; ks++) {
                bf16x8 kfr = *(const bf16x8*)&lK[nf*16 + r16][ks*32 + g4*8];
                sf[nf] = __builtin_amdgcn_mfma_f32_16x16x32_bf16(
                    qf[ks], kfr, sf[nf], 0, 0, 0);
            }
        int trow = t0 + wid*16 + g4*4;
        #pragma unroll
        for (int nf = 0; nf < 2; nf++)
            #pragma unroll
            for (int j = 0; j < 4; j++) {
                sf[nf][j] *= 0.125f;
                int ss = s0 + nf*16 + r16;
                if (ss > trow + j) sf[nf][j] = -1e30f;
            }
        float pm[4], al[4], ps[4];
        #pragma unroll
        for (int j = 0; j < 4; j++) pm[j] = fmaxf(sf[0][j], sf[1][j]);
        #pragma unroll
        for (int d = 1; d < 16; d <<= 1)
            #pragma unroll
            for (int j = 0; j < 4; j++) pm[j] = fmaxf(pm[j], __shfl_xor(pm[j], d));
        #pragma unroll
        for (int j = 0; j < 4; j++) {
            float mn = fmaxf(mrow[j], pm[j]);
            al[j] = __expf(mrow[j] - mn);
            mrow[j] = mn;
            ps[j] = 0.f;
        }
        #pragma unroll
        for (int nf = 0; nf < 2; nf++)
            #pragma unroll
            for (int j = 0; j < 4; j++) {
                float p = __expf(sf[nf][j] - mrow[j]);
                ps[j] += p;
                lP[wid][g4*4 + j][nf*16 + r16] = (bf16)p;
            }
        #pragma unroll
        for (int d = 1; d < 16; d <<= 1)
            #pragma unroll
            for (int j = 0; j < 4; j++) ps[j] += __shfl_xor(ps[j], d);
        #pragma unroll
        for (int j = 0; j < 4; j++) lrow[j] = lrow[j] * al[j] + ps[j];
        #pragma unroll
        for (int nf = 0; nf < 4; nf++)
            #pragma unroll
            for (int j = 0; j < 4; j++) oacc[nf][j] *= al[j];
        __syncthreads();

        bf16x8 pa = *(const bf16x8*)&lP[wid][r16][g4*8];
        #pragma unroll
        for (int nf = 0; nf < 4; nf++) {
            bf16x8 vfr = *(const bf16x8*)&lVT[nf*16 + r16][g4*8];
            oacc[nf] = __builtin_amdgcn_mfma_f32_16x16x32_bf16(
                pa, vfr, oacc[nf], 0, 0, 0);
        }
        __syncthreads();
    }

    #pragma unroll
    for (int nf = 0; nf < 4; nf++) {
        #pragma unroll
        for (int j = 0; j < 4; j++) {
            int trow = t0 + wid*16 + g4*4 + j;
            float val = oacc[nf][j] / lrow[j];
            op[(size_t)trow * DD + nf*16 + r16] = (bf16)val;
        }
    }
}

// ---------------------------------------------------------------- launcher
extern "C" void kernel_launch(void* const* d_in, const int* in_sizes, int n_in,
                              void* d_out, int out_size, void* d_ws, size_t ws_size,
                              hipStream_t stream)
{
    (void)in_sizes; (void)n_in; (void)out_size;
    const int*   x    = (const int*)  d_in[0];
    const float* tok  = (const float*)d_in[1];
    const float* pos  = (const float*)d_in[2];
    const float* ln1g = (const float*)d_in[3];
    const float* ln1b = (const float*)d_in[4];
    const float* wq   = (const float*)d_in[5];
    const float* bq   = (const float*)d_in[6];
    const float* wk   = (const float*)d_in[7];
    const float* bk   = (const float*)d_in[8];
    const float* wv   = (const float*)d_in[9];
    const float* bv   = (const float*)d_in[10];
    const float* wo   = (const float*)d_in[11];
    const float* bo   = (const float*)d_in[12];
    const float* ln2g = (const float*)d_in[13];
    const float* ln2b = (const float*)d_in[14];
    const float* w1   = (const float*)d_in[15];
    const float* b1   = (const float*)d_in[16];
    const float* w2   = (const float*)d_in[17];
    const float* b2   = (const float*)d_in[18];
    const float* lnfg = (const float*)d_in[19];
    const float* lnfb = (const float*)d_in[20];
    const float* fcw  = (const float*)d_in[21];
    const float* fcb  = (const float*)d_in[22];

    const size_t MB = (size_t)1 << 20;
    // d_out scratch map (all dead before final logits write):
    char*  sb   = (char*)d_out;
    float* h    = (float*)(sb);                    // 16 MB
    float* hn   = (float*)(sb + 16*MB);            // 16 MB
    bf16*  hnb  = (bf16*) (sb + 32*MB);            //  8 MB
    bf16*  qkv  = (bf16*) (sb + 40*MB);            // 24 MB [4096][3072]
    bf16*  obuf = (bf16*) (sb + 64*MB);            //  8 MB
    bf16*  f1b  = (bf16*) (sb + 72*MB);            // 32 MB -> ends 104 MB
    bf16*  WT   = (bf16*) (sb + 104*MB);           // 288 MB packed B^T -> ends 392 MB
    float* bqkv = (float*)(sb + 392*MB);           // 147 KB
    bf16*  hfb  = (bf16*) d_ws;                    //  8 MB (survives logits write)

    const size_t LWT = 12582912;                   // per-layer WT elems (24 MB)
    const size_t FCWT_BYTES = (size_t)VP * DD * 2; // 103 MB
    bool fast_logits = (ws_size >= 8*MB + FCWT_BYTES);
    bf16* fcwT = (bf16*)((char*)d_ws + 8*MB);

    dim3 blk(256);

    // ---- weight prepack (B^T bf16) ----
    k_wtrans<<<dim3(4, 32, 12), blk, 0, stream>>>(wq, WT,               DD, DD, DD, (size_t)DD*DD, LWT);
    k_wtrans<<<dim3(4, 32, 12), blk, 0, stream>>>(wk, WT + 1024*1024,   DD, DD, DD, (size_t)DD*DD, LWT);
    k_wtrans<<<dim3(4, 32, 12), blk, 0, stream>>>(wv, WT + 2048*1024,   DD, DD, DD, (size_t)DD*DD, LWT);
    k_wtrans<<<dim3(4, 32, 12), blk, 0, stream>>>(wo, WT + 3145728,     DD, DD, DD, (size_t)DD*DD, LWT);
    k_wtrans<<<dim3(16, 32, 12), blk, 0, stream>>>(w1, WT + 4194304,    DD, FF, FF, (size_t)DD*FF, LWT);
    k_wtrans<<<dim3(4, 128, 12), blk, 0, stream>>>(w2, WT + 8388608,    FF, DD, DD, (size_t)FF*DD, LWT);
    if (fast_logits)
        k_wtrans<<<dim3(197, 32, 1), blk, 0, stream>>>(fcw, fcwT, DD, VV, VP, 0, 0);
    k_biasmerge<<<dim3(144), blk, 0, stream>>>(bq, bk, bv, bqkv);

    // ---- trunk ----
    k_embed<<<MM, blk, 0, stream>>>(x, tok, pos, h);
    for (int l = 0; l < LL; l++) {
        const bf16* WTl = WT + (size_t)l * LWT;
        k_ln<<<MM, blk, 0, stream>>>(h, ln1g + l*DD, ln1b + l*DD, hn, hnb);
        k_gemm_bt<<<dim3(24, 32), blk, 0, stream>>>(hnb, WTl, bqkv + l*QS,
                                                    nullptr, nullptr, qkv, DD, QS, 0);
        k_attn<<<dim3(TT/64, BB*HH), blk, 0, stream>>>(qkv, obuf);
        k_gemm_bt<<<dim3(8, 32), blk, 0, stream>>>(obuf, WTl + 3145728, bo + l*DD,
                                                   hn, h, nullptr, DD, DD, 0);
        k_ln<<<MM, blk, 0, stream>>>(h, ln2g + l*DD, ln2b + l*DD, hn, hnb);
        k_gemm_bt<<<dim3(32, 32), blk, 0, stream>>>(hnb, WTl + 4194304, b1 + l*FF,
                                                    nullptr, nullptr, f1b, DD, FF, 1);
        k_gemm_bt<<<dim3(8, 32), blk, 0, stream>>>(f1b, WTl + 8388608, b2 + l*DD,
                                                   hn, h, nullptr, FF, DD, 0);
    }
    k_ln<<<MM, blk, 0, stream>>>(h, lnfg, lnfb, nullptr, hfb);

    // ---- logits ----
    if (fast_logits) {
        k_gemm_bt<<<dim3(VP/128, 32), blk, 0, stream>>>(hfb, fcwT, fcb,
                                                        nullptr, (float*)d_out, nullptr,
                                                        DD, VV, 0);
    } else {
        k_gemm_f32b<<<dim3(32, (VV + 127)/128), blk, 0, stream>>>(hfb, fcw, fcb,
                                                                  (float*)d_out, MM, VV, DD);
    }
}